// Round 2
// 152.490 us; speedup vs baseline: 1.0217x; 1.0217x over previous
//
#include <hip/hip_runtime.h>
#include <hip/hip_bf16.h>

#define B_ 128
#define F_ 100
#define N_ 512
#define H_ 1024
#define P_ 512
#define E_ 8
#define BK 64
#define AROWS 112  // staged A rows (M=100 rounded to DMA granularity of 8)

typedef __attribute__((ext_vector_type(8))) short bf16x8;
typedef __attribute__((ext_vector_type(4))) float f32x4;

// async global->LDS DMA, 16B/lane, LDS dest = wave-uniform base + lane*16
#define GLOAD16(g, l) __builtin_amdgcn_global_load_lds(                      \
    (const __attribute__((address_space(1))) void*)(g),                      \
    (__attribute__((address_space(3))) void*)(l), 16, 0, 0)

static __device__ __forceinline__ short f2bf(float f) {
    __hip_bfloat16 h = __float2bfloat16(f);
    short s;
    __builtin_memcpy(&s, &h, sizeof(s));
    return s;
}

// ONE prep kernel, grid sections:
//   [0,3200)      convert x [B][F][N] fp32 -> xbf [12800][N] bf16 (linear)
//   [3200,4224)   transpose W1 [E][512][1024] -> W1T [E][1024][512] bf16
//   [4224,5248)   transpose W2 [E][1024][512] -> W2T [E][512][1024] bf16
//   5248          tile table sorted by expert (data stays in trial order):
//                 ttab[slot]=(trial,eid); GEMM slot s -> XCD s%8-grouped so
//                 each XCD sees 16 expert-contiguous trials (1-2 experts).
__global__ __launch_bounds__(256) void prep(
    const float* __restrict__ x, const float* __restrict__ W1,
    const float* __restrict__ W2, const int* __restrict__ eid,
    short* __restrict__ xbf, short* __restrict__ W1T, short* __restrict__ W2T,
    int2* __restrict__ ttab) {
    __shared__ float tile[64][65];
    __shared__ int scnt[E_], sbase[E_];
    const int bx = blockIdx.x;
    const int t = threadIdx.x;
    if (bx < 3200) {  // ---- convert x ----
        const int g = bx * 256 + t;
        const int col = (g & 63) * 8;
        const int row = g >> 6;  // 0..12799
        const float* xp = x + (size_t)row * N_ + col;
        const float4 v0 = *(const float4*)(xp);
        const float4 v1 = *(const float4*)(xp + 4);
        union { short s[8]; uint4 u; } o;
        o.s[0] = f2bf(v0.x); o.s[1] = f2bf(v0.y);
        o.s[2] = f2bf(v0.z); o.s[3] = f2bf(v0.w);
        o.s[4] = f2bf(v1.x); o.s[5] = f2bf(v1.y);
        o.s[6] = f2bf(v1.z); o.s[7] = f2bf(v1.w);
        *(uint4*)(xbf + (size_t)row * N_ + col) = o.u;
    } else if (bx < 5248) {  // ---- weight transpose+convert ----
        const float* W; short* WT; int R, C, r0, c0, e;
        if (bx < 4224) {
            const int idx = bx - 3200;
            e = idx >> 7; const int i = idx & 127;
            W = W1; WT = W1T; R = N_; C = H_;
            r0 = (i >> 4) * 64; c0 = (i & 15) * 64;
        } else {
            const int idx = bx - 4224;
            e = idx >> 7; const int i = idx & 127;
            W = W2; WT = W2T; R = H_; C = P_;
            r0 = (i & 15) * 64; c0 = (i >> 4) * 64;
        }
        const float* Wp = W + (size_t)e * R * C;
        short* WTp = WT + (size_t)e * C * R;
        {
            const int c4 = (t & 15) * 4, r = t >> 4;
#pragma unroll
            for (int p = 0; p < 4; p++) {
                const int row = p * 16 + r;
                const float4 v = *(const float4*)(Wp + (size_t)(r0 + row) * C + c0 + c4);
                tile[row][c4 + 0] = v.x; tile[row][c4 + 1] = v.y;
                tile[row][c4 + 2] = v.z; tile[row][c4 + 3] = v.w;
            }
        }
        __syncthreads();
        {
            const int r8 = (t & 7) * 8, cl = t >> 3;
#pragma unroll
            for (int p = 0; p < 2; p++) {
                const int c = p * 32 + cl;
                union { short s[8]; uint4 u; } o;
#pragma unroll
                for (int j = 0; j < 8; j++) o.s[j] = f2bf(tile[r8 + j][c]);
                *(uint4*)(&WTp[(size_t)(c0 + c) * R + r0 + r8]) = o.u;
            }
        }
    } else {  // ---- tile-table sort (one block) ----
        if (t < E_) scnt[t] = 0;
        __syncthreads();
        int my_e = 0;
        if (t < B_) { my_e = eid[t]; atomicAdd(&scnt[my_e], 1); }
        __syncthreads();
        if (t == 0) {
            int s = 0;
            for (int i = 0; i < E_; i++) { sbase[i] = s; s += scnt[i]; }
        }
        __syncthreads();
        if (t < B_) {
            const int pos = atomicAdd(&sbase[my_e], 1);
            ttab[pos] = make_int2(t, my_e);
        }
    }
}

// 128xBN_ tile GEMM, one TRIAL per m-tile. A staged rows 0..111 only (14 DMA;
// sA is compacted to 112 rows -- rows 112..127 of the M-tile don't exist in
// LDS at all, keeping DBUF static LDS at 60 KiB < the 64 KiB limit).
// Wave-rows >=100 skipped via wave-uniform branch with compile-time register
// indices. BK=64, 4 waves 2x2, async global_load_lds staging, XOR-swizzled
// LDS (swizzle applied on the GLOBAL address; LDS dest stays linear).
// DBUF=true (gemm2): grid is 512 blocks = exactly 2 blocks/CU, so the 60 KiB
// double-buffer is occupancy-free -> stage(next) BEFORE compute(cur), ONE
// barrier per K-step; the compiler's vmcnt(0)-before-s_barrier drain then
// lands after the MFMA phase instead of immediately after issue (T3 minimum
// 2-phase recipe), hiding global latency that 2 resident blocks can't.
// DBUF=false (gemm1): original stage/sync/compute/sync, 4 blocks/CU.
// Epilogue: acc -> per-wave LDS -> 16B coalesced stores. fp32 epilogue runs
// NI/2 passes of 32 cols @ 8 KiB/wave (per-wave private, no barrier).
// FIRST:  act[(trial*100+row)][col] = softsign(xbf @ W1T^T + b1), bf16
// !FIRST: out[trial][row][col]      = act @ W2T^T + b2, fp32   (row < 100)
template <int KDIM, int BN_, bool FIRST, int MINW, bool DBUF>
__global__ __launch_bounds__(256, MINW) void gemm_kernel(
    const short* __restrict__ A,     // [B_*F_+128pad][KDIM] bf16, K-contig
    const short* __restrict__ WT,    // [E][NCOLS][KDIM] bf16, K-contig
    const float* __restrict__ bias,  // [E][NCOLS]
    const int2* __restrict__ ttab,   // [B_] (trial, expert), expert-sorted
    short* __restrict__ actout,      // FIRST
    float* __restrict__ out)         // !FIRST
{
    constexpr int NCOLS = FIRST ? H_ : P_;
    constexpr int NI = BN_ / 32;                   // n-frags per wave
    constexpr int STAGE1 = (AROWS + BN_) * BK;     // shorts per staging buffer
    constexpr int NBUF = DBUF ? 2 : 1;
    constexpr int EPI_SH = 4 * 4096;               // 4 waves x 8 KiB
    constexpr int SBUF_SH = (STAGE1 * NBUF > EPI_SH) ? STAGE1 * NBUF : EPI_SH;
    __shared__ short sbuf[SBUF_SH];
    const int slot = (blockIdx.x & 7) * 16 + (blockIdx.x >> 3);
    const int2 te = ttab[slot];
    const int trial = te.x, e = te.y;
    const int n0 = blockIdx.y * BN_;
    const int t = threadIdx.x;
    const int lane = t & 63, w = t >> 6;
    const int wm = (w >> 1) * 64, wn = (w & 1) * (BN_ / 2);
    const int l15 = lane & 15, quad = lane >> 4;
    const int lr = lane >> 3;                 // staging row 0..7
    const int lc = (((lane & 7) ^ lr) * 8);   // XOR-swizzled col chunk

    f32x4 acc[4][NI];
#pragma unroll
    for (int mi = 0; mi < 4; mi++)
#pragma unroll
        for (int ni = 0; ni < NI; ni++)
            acc[mi][ni] = (f32x4)(0.0f);

    // hoist bias (depends on ni only)
    float bv[NI];
#pragma unroll
    for (int ni = 0; ni < NI; ni++)
        bv[ni] = bias[(size_t)e * NCOLS + n0 + wn + ni * 16 + l15];

    const short* Ap = A + (size_t)trial * F_ * KDIM;
    const short* Bp = WT + ((size_t)e * NCOLS + n0) * KDIM;

    auto stage = [&](int k0, short* sbase) {
        short* sA = sbase;
        short* sB = sbase + AROWS * BK;
#pragma unroll
        for (int i = 0; i < 4; i++) {
            const int rb = w * 32 + i * 8;
            if (rb < AROWS)  // wave-uniform; rows 112..127 never read
                GLOAD16(Ap + (size_t)(rb + lr) * KDIM + k0 + lc, &sA[rb * BK]);
        }
#pragma unroll
        for (int i = 0; i < NI; i++) {
            const int rb = w * (BN_ / 4) + i * 8;
            GLOAD16(Bp + (size_t)(rb + lr) * KDIM + k0 + lc, &sB[rb * BK]);
        }
    };

    auto compute = [&](const short* sbase) {
        const short* sA = sbase;
        const short* sB = sbase + AROWS * BK;
#pragma unroll
        for (int ks = 0; ks < 2; ks++) {
            const int sw = (((ks * 4 + quad) ^ (l15 & 7)) * 8);
            bf16x8 af, bfr[NI];
#pragma unroll
            for (int ni = 0; ni < NI; ni++)
                bfr[ni] = *(const bf16x8*)(&sB[(wn + ni * 16 + l15) * BK + sw]);
#pragma unroll
            for (int mi = 0; mi < 4; mi++) {
                if (wm + mi * 16 < F_) {  // wave-uniform; indices constant
                    af = *(const bf16x8*)(&sA[(wm + mi * 16 + l15) * BK + sw]);
#pragma unroll
                    for (int ni = 0; ni < NI; ni++)
                        acc[mi][ni] = __builtin_amdgcn_mfma_f32_16x16x32_bf16(af, bfr[ni], acc[mi][ni], 0, 0, 0);
                }
            }
        }
    };

    if constexpr (DBUF) {
        // double-buffered: stage(next) before compute(cur), 1 barrier/K-step.
        // KDIM/BK is even (1024/64=16) -> static buffer parity.
        short* b0 = sbuf;
        short* b1 = sbuf + STAGE1;
        stage(0, b0);
        __syncthreads();  // drains vmcnt(0): buf0 ready
        for (int k0 = 0; k0 < KDIM; k0 += 2 * BK) {
            stage(k0 + BK, b1);
            compute(b0);
            __syncthreads();  // drains: buf1 ready, buf0 reads done
            if (k0 + 2 * BK < KDIM) stage(k0 + 2 * BK, b0);
            compute(b1);
            __syncthreads();
        }
    } else {
        for (int k0 = 0; k0 < KDIM; k0 += BK) {
            stage(k0, sbuf);
            __syncthreads();
            compute(sbuf);
            __syncthreads();  // also protects sbuf reuse by the epilogue
        }
    }

    // ---- epilogue via per-wave LDS transpose -> coalesced 16B stores ----
    // C/D frag layout: col=lane&15, row=quad*4+reg.
    if constexpr (FIRST) {
        short* sW = sbuf + w * 4096;  // 64 rows x 64 bf16, chunk^=(row&7)
#pragma unroll
        for (int mi = 0; mi < 4; mi++) {
#pragma unroll
            for (int ni = 0; ni < 4; ni++) {
                const int cl = ni * 16 + l15;
#pragma unroll
                for (int r = 0; r < 4; r++) {
                    const int rl = mi * 16 + quad * 4 + r;  // 0..63
                    float v = acc[mi][ni][r] + bv[ni];
                    v = v / (1.0f + fabsf(v));  // softsign, SCALE=1
                    sW[rl * 64 + (((cl >> 3) ^ (rl & 7)) * 8) + (cl & 7)] = f2bf(v);
                }
            }
        }
#pragma unroll
        for (int i = 0; i < 8; i++) {
            const int rl = i * 8 + lr;        // 0..63 (rl&7 == lr)
            const int c = lane & 7;
            const bf16x8 v = *(const bf16x8*)(&sW[rl * 64 + ((c ^ lr) * 8)]);
            const int grow = wm + rl;
            if (grow < F_)
                *(bf16x8*)(&actout[((size_t)trial * F_ + grow) * H_ + n0 + wn + c * 8]) = v;
        }
    } else {
        float* fW = (float*)(sbuf) + w * 2048;  // 64 rows x 32 fp32 per wave
#pragma unroll
        for (int pass = 0; pass < NI; pass += 2) {
#pragma unroll
            for (int mi = 0; mi < 4; mi++) {
#pragma unroll
                for (int nj = 0; nj < 2; nj++) {
                    const int cl = nj * 16 + l15;   // 0..31
#pragma unroll
                    for (int r = 0; r < 4; r++) {
                        const int rl = mi * 16 + quad * 4 + r;  // 0..63
                        fW[rl * 32 + (((cl >> 2) ^ (rl & 7)) * 4) + (cl & 3)] =
                            acc[mi][pass + nj][r] + bv[pass + nj];
                    }
                }
            }
#pragma unroll
            for (int i = 0; i < 8; i++) {
                const int rl = i * 8 + lr;           // 0..63 (rl&7 == lr)
                const int c = lane & 7;              // 16B chunk, 32 cols = 8 chunks
                const float4 v = *(const float4*)(&fW[rl * 32 + ((c ^ lr) * 4)]);
                const int grow = wm + rl;
                if (grow < F_)
                    *(float4*)(&out[((size_t)trial * F_ + grow) * P_ + n0 + wn + pass * 16 + c * 4]) = v;
            }
            // per-wave private buffer; same-wave RAW across passes is ordered
            // by compiler-inserted lgkmcnt waits -> no barrier needed.
        }
    }
}

extern "C" void kernel_launch(void* const* d_in, const int* in_sizes, int n_in,
                              void* d_out, int out_size, void* d_ws, size_t ws_size,
                              hipStream_t stream) {
    const float* x  = (const float*)d_in[0];
    const int* eid  = (const int*)d_in[1];
    const float* W1 = (const float*)d_in[2];
    const float* b1 = (const float*)d_in[3];
    const float* W2 = (const float*)d_in[4];
    const float* b2 = (const float*)d_in[5];
    float* out = (float*)d_out;

    char* ws = (char*)d_ws;
    short* W1T = (short*)(ws);                          // [E][H][N]      8 MiB
    short* W2T = (short*)(ws + (size_t)(8u << 20));     // [E][P][H]      8 MiB
    short* act = (short*)(ws + (size_t)(16u << 20));    // [12800+128][H] ~26.5 MiB
    short* xbf = (short*)(ws + (size_t)(43u << 20));    // [12800+128][N] ~13.3 MiB
    int2* ttab = (int2*)(ws + (size_t)(57u << 20));     // [B_]

    prep<<<dim3(5249), 256, 0, stream>>>(x, W1, W2, eid, xbf, W1T, W2T, ttab);
    // gemm1: 1024 blocks (4/CU), single-buffer, unchanged schedule.
    gemm_kernel<N_, 128, true, 4, false><<<dim3(B_, H_ / 128), 256, 0, stream>>>(xbf, W1T, b1, ttab, act, nullptr);
    // gemm2: BN 64->128 (LDS intensity 21->32 FLOP/B), 512 blocks = exactly
    // 2/CU, 60 KiB double-buffer (occupancy-free), 1 barrier per K-step.
    gemm_kernel<H_, 128, false, 2, true><<<dim3(B_, P_ / 128), 256, 0, stream>>>(act, W2T, b2, ttab, nullptr, out);
}

// Round 3
// 151.213 us; speedup vs baseline: 1.0303x; 1.0084x over previous
//
#include <hip/hip_runtime.h>
#include <hip/hip_bf16.h>

#define B_ 128
#define F_ 100
#define N_ 512
#define H_ 1024
#define P_ 512
#define E_ 8
#define BK 64
#define AROWS 112  // staged A rows (M=100 rounded to DMA granularity of 8)

typedef __attribute__((ext_vector_type(8))) short bf16x8;
typedef __attribute__((ext_vector_type(4))) float f32x4;

// async global->LDS DMA, 16B/lane, LDS dest = wave-uniform base + lane*16
#define GLOAD16(g, l) __builtin_amdgcn_global_load_lds(                      \
    (const __attribute__((address_space(1))) void*)(g),                      \
    (__attribute__((address_space(3))) void*)(l), 16, 0, 0)

static __device__ __forceinline__ short f2bf(float f) {
    __hip_bfloat16 h = __float2bfloat16(f);
    short s;
    __builtin_memcpy(&s, &h, sizeof(s));
    return s;
}

// ONE prep kernel, grid sections:
//   [0,3200)      convert x [B][F][N] fp32 -> xbf [12800][N] bf16 (linear)
//   [3200,4224)   transpose W1 [E][512][1024] -> W1T [E][1024][512] bf16
//   [4224,5248)   transpose W2 [E][1024][512] -> W2T [E][512][1024] bf16
//   5248          tile table sorted by expert (data stays in trial order):
//                 ttab[slot]=(trial,eid); GEMM slot s -> XCD s%8-grouped so
//                 each XCD sees 16 expert-contiguous trials (1-2 experts).
__global__ __launch_bounds__(256) void prep(
    const float* __restrict__ x, const float* __restrict__ W1,
    const float* __restrict__ W2, const int* __restrict__ eid,
    short* __restrict__ xbf, short* __restrict__ W1T, short* __restrict__ W2T,
    int2* __restrict__ ttab) {
    __shared__ float tile[64][65];
    __shared__ int scnt[E_], sbase[E_];
    const int bx = blockIdx.x;
    const int t = threadIdx.x;
    if (bx < 3200) {  // ---- convert x ----
        const int g = bx * 256 + t;
        const int col = (g & 63) * 8;
        const int row = g >> 6;  // 0..12799
        const float* xp = x + (size_t)row * N_ + col;
        const float4 v0 = *(const float4*)(xp);
        const float4 v1 = *(const float4*)(xp + 4);
        union { short s[8]; uint4 u; } o;
        o.s[0] = f2bf(v0.x); o.s[1] = f2bf(v0.y);
        o.s[2] = f2bf(v0.z); o.s[3] = f2bf(v0.w);
        o.s[4] = f2bf(v1.x); o.s[5] = f2bf(v1.y);
        o.s[6] = f2bf(v1.z); o.s[7] = f2bf(v1.w);
        *(uint4*)(xbf + (size_t)row * N_ + col) = o.u;
    } else if (bx < 5248) {  // ---- weight transpose+convert ----
        const float* W; short* WT; int R, C, r0, c0, e;
        if (bx < 4224) {
            const int idx = bx - 3200;
            e = idx >> 7; const int i = idx & 127;
            W = W1; WT = W1T; R = N_; C = H_;
            r0 = (i >> 4) * 64; c0 = (i & 15) * 64;
        } else {
            const int idx = bx - 4224;
            e = idx >> 7; const int i = idx & 127;
            W = W2; WT = W2T; R = H_; C = P_;
            r0 = (i & 15) * 64; c0 = (i >> 4) * 64;
        }
        const float* Wp = W + (size_t)e * R * C;
        short* WTp = WT + (size_t)e * C * R;
        {
            const int c4 = (t & 15) * 4, r = t >> 4;
#pragma unroll
            for (int p = 0; p < 4; p++) {
                const int row = p * 16 + r;
                const float4 v = *(const float4*)(Wp + (size_t)(r0 + row) * C + c0 + c4);
                tile[row][c4 + 0] = v.x; tile[row][c4 + 1] = v.y;
                tile[row][c4 + 2] = v.z; tile[row][c4 + 3] = v.w;
            }
        }
        __syncthreads();
        {
            const int r8 = (t & 7) * 8, cl = t >> 3;
#pragma unroll
            for (int p = 0; p < 2; p++) {
                const int c = p * 32 + cl;
                union { short s[8]; uint4 u; } o;
#pragma unroll
                for (int j = 0; j < 8; j++) o.s[j] = f2bf(tile[r8 + j][c]);
                *(uint4*)(&WTp[(size_t)(c0 + c) * R + r0 + r8]) = o.u;
            }
        }
    } else {  // ---- tile-table sort (one block) ----
        if (t < E_) scnt[t] = 0;
        __syncthreads();
        int my_e = 0;
        if (t < B_) { my_e = eid[t]; atomicAdd(&scnt[my_e], 1); }
        __syncthreads();
        if (t == 0) {
            int s = 0;
            for (int i = 0; i < E_; i++) { sbase[i] = s; s += scnt[i]; }
        }
        __syncthreads();
        if (t < B_) {
            const int pos = atomicAdd(&sbase[my_e], 1);
            ttab[pos] = make_int2(t, my_e);
        }
    }
}

// 128xBN_ tile GEMM, one TRIAL per m-tile. A staged rows 0..111 only (14 DMA
// per block; sA compacted to 112 rows -> dbuf static LDS 60 KiB < 64 KiB).
// Wave-rows >=100 skipped via wave-uniform branch, compile-time indices.
// BK=64, 4 waves 2x2, async global_load_lds, XOR-swizzle on GLOBAL address.
//
// T4 counted-vmcnt pipeline (both gemms): double-buffered K-loop where the
// pre-compute barrier is raw s_barrier preceded by a COUNTED s_waitcnt
// (vmcnt(8)/vmcnt(6) = this stage's own issue count), so the just-issued
// next-tile DMAs stay in flight across the barrier and only the previous
// tile's loads are retired. __syncthreads() (which drains vmcnt(0) and
// defeats the prefetch) appears nowhere in the K-loop. The trailing
// barrier (protects buffer about to be restaged; ds_reads already retired
// by the compiler's lgkmcnt before the last MFMA) is a plain s_barrier.
// Per-wave DMA issue counts: waves 0-2 = 4A+4B = 8, wave 3 = 2A+4B = 6.
// Tail peeled: last K-step waits vmcnt(0). 2 blocks/CU (60KiB LDS), MINW=2.
//
// Epilogue: acc -> per-wave LDS -> 16B coalesced stores; fp32 path runs
// NI/2 passes of 32 cols @ 8 KiB/wave (per-wave private, no barrier).
// FIRST:  act[(trial*100+row)][col] = softsign(xbf @ W1T^T + b1), bf16
// !FIRST: out[trial][row][col]      = act @ W2T^T + b2, fp32   (row < 100)
template <int KDIM, int BN_, bool FIRST>
__global__ __launch_bounds__(256, 2) void gemm_kernel(
    const short* __restrict__ A,     // [B_*F_+128pad][KDIM] bf16, K-contig
    const short* __restrict__ WT,    // [E][NCOLS][KDIM] bf16, K-contig
    const float* __restrict__ bias,  // [E][NCOLS]
    const int2* __restrict__ ttab,   // [B_] (trial, expert), expert-sorted
    short* __restrict__ actout,      // FIRST
    float* __restrict__ out)         // !FIRST
{
    constexpr int NCOLS = FIRST ? H_ : P_;
    constexpr int NI = BN_ / 32;                   // n-frags per wave
    constexpr int STAGE1 = (AROWS + BN_) * BK;     // shorts per staging buffer
    constexpr int EPI_SH = 4 * 4096;               // 4 waves x 8 KiB
    constexpr int SBUF_SH = (2 * STAGE1 > EPI_SH) ? 2 * STAGE1 : EPI_SH;
    __shared__ short sbuf[SBUF_SH];
    const int slot = (blockIdx.x & 7) * 16 + (blockIdx.x >> 3);
    const int2 te = ttab[slot];
    const int trial = te.x, e = te.y;
    const int n0 = blockIdx.y * BN_;
    const int t = threadIdx.x;
    const int lane = t & 63, w = t >> 6;
    const int wm = (w >> 1) * 64, wn = (w & 1) * (BN_ / 2);
    const int l15 = lane & 15, quad = lane >> 4;
    const int lr = lane >> 3;                 // staging row 0..7
    const int lc = (((lane & 7) ^ lr) * 8);   // XOR-swizzled col chunk

    f32x4 acc[4][NI];
#pragma unroll
    for (int mi = 0; mi < 4; mi++)
#pragma unroll
        for (int ni = 0; ni < NI; ni++)
            acc[mi][ni] = (f32x4)(0.0f);

    // hoist bias (depends on ni only)
    float bv[NI];
#pragma unroll
    for (int ni = 0; ni < NI; ni++)
        bv[ni] = bias[(size_t)e * NCOLS + n0 + wn + ni * 16 + l15];

    const short* Ap = A + (size_t)trial * F_ * KDIM;
    const short* Bp = WT + ((size_t)e * NCOLS + n0) * KDIM;

    auto stage = [&](int k0, short* sb) {
        short* sA = sb;
        short* sB = sb + AROWS * BK;
#pragma unroll
        for (int i = 0; i < 4; i++) {
            const int rb = w * 32 + i * 8;
            if (rb < AROWS)  // wave-uniform; waves 0-2: 4 DMAs, wave 3: 2
                GLOAD16(Ap + (size_t)(rb + lr) * KDIM + k0 + lc, &sA[rb * BK]);
        }
#pragma unroll
        for (int i = 0; i < NI; i++) {
            const int rb = w * (BN_ / 4) + i * 8;
            GLOAD16(Bp + (size_t)(rb + lr) * KDIM + k0 + lc, &sB[rb * BK]);
        }
    };

    auto compute = [&](const short* sb) {
        const short* sA = sb;
        const short* sB = sb + AROWS * BK;
#pragma unroll
        for (int ks = 0; ks < 2; ks++) {
            const int sw = (((ks * 4 + quad) ^ (l15 & 7)) * 8);
            bf16x8 af, bfr[NI];
#pragma unroll
            for (int ni = 0; ni < NI; ni++)
                bfr[ni] = *(const bf16x8*)(&sB[(wn + ni * 16 + l15) * BK + sw]);
#pragma unroll
            for (int mi = 0; mi < 4; mi++) {
                if (wm + mi * 16 < F_) {  // wave-uniform; indices constant
                    af = *(const bf16x8*)(&sA[(wm + mi * 16 + l15) * BK + sw]);
#pragma unroll
                    for (int ni = 0; ni < NI; ni++)
                        acc[mi][ni] = __builtin_amdgcn_mfma_f32_16x16x32_bf16(af, bfr[ni], acc[mi][ni], 0, 0, 0);
                }
            }
        }
    };

    // counted wait: retire exactly the PREVIOUS stage's DMAs (own counts:
    // waves 0-2 issue 8/stage, wave 3 issues 6/stage). Wave-uniform branch.
    auto wait_prev_and_bar = [&]() {
        if (w < 3) asm volatile("s_waitcnt vmcnt(8)" ::: "memory");
        else       asm volatile("s_waitcnt vmcnt(6)" ::: "memory");
        __builtin_amdgcn_s_barrier();
        __builtin_amdgcn_sched_barrier(0);
    };
    auto bar = [&]() {  // plain exec barrier, no drain
        __builtin_amdgcn_sched_barrier(0);
        __builtin_amdgcn_s_barrier();
        __builtin_amdgcn_sched_barrier(0);
    };

    short* b0 = sbuf;
    short* b1 = sbuf + STAGE1;

    // KDIM/BK even (8 or 16): 2 K-steps per iteration, static buffer parity.
    stage(0, b0);
    for (int k0 = 0; k0 < KDIM - 2 * BK; k0 += 2 * BK) {
        stage(k0 + BK, b1);
        wait_prev_and_bar();        // b0 ready; b1 loads remain in flight
        compute(b0);
        bar();                      // b0 reads done -> safe to restage b0
        stage(k0 + 2 * BK, b0);
        wait_prev_and_bar();        // b1 ready
        compute(b1);
        bar();
    }
    // tail: steps KDIM-2BK (in b0) and KDIM-BK
    stage(KDIM - BK, b1);
    wait_prev_and_bar();
    compute(b0);
    bar();
    asm volatile("s_waitcnt vmcnt(0)" ::: "memory");
    __builtin_amdgcn_s_barrier();
    __builtin_amdgcn_sched_barrier(0);
    compute(b1);
    bar();                          // protect sbuf before epilogue reuse

    // ---- epilogue via per-wave LDS transpose -> coalesced 16B stores ----
    // C/D frag layout: col=lane&15, row=quad*4+reg.
    if constexpr (FIRST) {
        short* sW = sbuf + w * 4096;  // 64 rows x 64 bf16, chunk^=(row&7)
#pragma unroll
        for (int mi = 0; mi < 4; mi++) {
#pragma unroll
            for (int ni = 0; ni < 4; ni++) {
                const int cl = ni * 16 + l15;
#pragma unroll
                for (int r = 0; r < 4; r++) {
                    const int rl = mi * 16 + quad * 4 + r;  // 0..63
                    float v = acc[mi][ni][r] + bv[ni];
                    v = v / (1.0f + fabsf(v));  // softsign, SCALE=1
                    sW[rl * 64 + (((cl >> 3) ^ (rl & 7)) * 8) + (cl & 7)] = f2bf(v);
                }
            }
        }
#pragma unroll
        for (int i = 0; i < 8; i++) {
            const int rl = i * 8 + lr;        // 0..63 (rl&7 == lr)
            const int c = lane & 7;
            const bf16x8 v = *(const bf16x8*)(&sW[rl * 64 + ((c ^ lr) * 8)]);
            const int grow = wm + rl;
            if (grow < F_)
                *(bf16x8*)(&actout[((size_t)trial * F_ + grow) * H_ + n0 + wn + c * 8]) = v;
        }
    } else {
        float* fW = (float*)(sbuf) + w * 2048;  // 64 rows x 32 fp32 per wave
#pragma unroll
        for (int pass = 0; pass < NI; pass += 2) {
#pragma unroll
            for (int mi = 0; mi < 4; mi++) {
#pragma unroll
                for (int nj = 0; nj < 2; nj++) {
                    const int cl = nj * 16 + l15;   // 0..31
#pragma unroll
                    for (int r = 0; r < 4; r++) {
                        const int rl = mi * 16 + quad * 4 + r;  // 0..63
                        fW[rl * 32 + (((cl >> 2) ^ (rl & 7)) * 4) + (cl & 3)] =
                            acc[mi][pass + nj][r] + bv[pass + nj];
                    }
                }
            }
#pragma unroll
            for (int i = 0; i < 8; i++) {
                const int rl = i * 8 + lr;           // 0..63 (rl&7 == lr)
                const int c = lane & 7;              // 16B chunk, 32 cols = 8 chunks
                const float4 v = *(const float4*)(&fW[rl * 32 + ((c ^ lr) * 4)]);
                const int grow = wm + rl;
                if (grow < F_)
                    *(float4*)(&out[((size_t)trial * F_ + grow) * P_ + n0 + wn + pass * 16 + c * 4]) = v;
            }
            // per-wave private buffer; same-wave RAW across passes is ordered
            // by compiler-inserted lgkmcnt waits -> no barrier needed.
        }
    }
}

extern "C" void kernel_launch(void* const* d_in, const int* in_sizes, int n_in,
                              void* d_out, int out_size, void* d_ws, size_t ws_size,
                              hipStream_t stream) {
    const float* x  = (const float*)d_in[0];
    const int* eid  = (const int*)d_in[1];
    const float* W1 = (const float*)d_in[2];
    const float* b1 = (const float*)d_in[3];
    const float* W2 = (const float*)d_in[4];
    const float* b2 = (const float*)d_in[5];
    float* out = (float*)d_out;

    char* ws = (char*)d_ws;
    short* W1T = (short*)(ws);                          // [E][H][N]      8 MiB
    short* W2T = (short*)(ws + (size_t)(8u << 20));     // [E][P][H]      8 MiB
    short* act = (short*)(ws + (size_t)(16u << 20));    // [12800+128][H] ~26.5 MiB
    short* xbf = (short*)(ws + (size_t)(43u << 20));    // [12800+128][N] ~13.3 MiB
    int2* ttab = (int2*)(ws + (size_t)(57u << 20));     // [B_]

    prep<<<dim3(5249), 256, 0, stream>>>(x, W1, W2, eid, xbf, W1T, W2T, ttab);
    // both gemms: 60 KiB dbuf, counted-vmcnt pipeline, 2 blocks/CU.
    gemm_kernel<N_, 128, true><<<dim3(B_, H_ / 128), 256, 0, stream>>>(xbf, W1T, b1, ttab, act, nullptr);
    gemm_kernel<H_, 128, false><<<dim3(B_, P_ / 128), 256, 0, stream>>>(act, W2T, b2, ttab, nullptr, out);
}